// Round 12
// baseline (226.505 us; speedup 1.0000x reference)
//
#include <hip/hip_runtime.h>
#include <hip/hip_fp16.h>
#include <math.h>

#define LSEQ 2048
#define NB 4
#define NH 8
#define DMID 512
#define CHK 128
#define SCALE 0.125f
#define DN 0.35355339059327373f   // 64^{-0.25}
#define DN2 0.125f                // DN*DN
#define LOG2E 1.4426950408889634f
#define EPS_ATTN 1e-5f
#define EPS_LN 1e-5f

typedef _Float16 f16x8 __attribute__((ext_vector_type(8)));
typedef _Float16 f16x4 __attribute__((ext_vector_type(4)));
typedef float f32x4 __attribute__((ext_vector_type(4)));

// Raw v_exp_f32 (2^x). Non-volatile: pure, freely schedulable.
__device__ __forceinline__ float exp2a(float x) {
  float r;
  asm("v_exp_f32 %0, %1" : "=v"(r) : "v"(x));
  return r;
}

__device__ __forceinline__ void cvt16(const float* __restrict__ p,
                                      _Float16* __restrict__ dst) {
  float4 a = *(const float4*)p, b = *(const float4*)(p + 4);
  float4 c = *(const float4*)(p + 8), d = *(const float4*)(p + 12);
  f16x8 t0 = {(_Float16)a.x, (_Float16)a.y, (_Float16)a.z, (_Float16)a.w,
              (_Float16)b.x, (_Float16)b.y, (_Float16)b.z, (_Float16)b.w};
  f16x8 t1 = {(_Float16)c.x, (_Float16)c.y, (_Float16)c.z, (_Float16)c.w,
              (_Float16)d.x, (_Float16)d.y, (_Float16)d.z, (_Float16)d.w};
  *(f16x8*)dst = t0;
  *(f16x8*)(dst + 8) = t1;
}

// Convert 4 prefetched float4 regs -> 16 fp16 in LDS.
__device__ __forceinline__ void cvt16r(const float4* __restrict__ r,
                                       _Float16* __restrict__ dst) {
  f16x8 t0 = {(_Float16)r[0].x, (_Float16)r[0].y, (_Float16)r[0].z,
              (_Float16)r[0].w, (_Float16)r[1].x, (_Float16)r[1].y,
              (_Float16)r[1].z, (_Float16)r[1].w};
  f16x8 t1 = {(_Float16)r[2].x, (_Float16)r[2].y, (_Float16)r[2].z,
              (_Float16)r[2].w, (_Float16)r[3].x, (_Float16)r[3].y,
              (_Float16)r[3].z, (_Float16)r[3].w};
  *(f16x8*)dst = t0;
  *(f16x8*)(dst + 8) = t1;
}

// Convert 2 prefetched float4 regs -> 8 fp16 in LDS.
__device__ __forceinline__ void cvt8r(const float4* __restrict__ r,
                                      _Float16* __restrict__ dst) {
  f16x8 t0 = {(_Float16)r[0].x, (_Float16)r[0].y, (_Float16)r[0].z,
              (_Float16)r[0].w, (_Float16)r[1].x, (_Float16)r[1].y,
              (_Float16)r[1].z, (_Float16)r[1].w};
  *(f16x8*)dst = t0;
}

// Diagnostic: encode ws_size (MiB) into the output if workspace too small.
__global__ void k_diag(float* out, int n, float val) {
  int i = blockIdx.x * 256 + threadIdx.x;
  if (i < n) out[i] = val;
}

// Once-per-launch: projT[n][k] = DN*LOG2E * proj[k][n], fp16.
__global__ __launch_bounds__(256) void k_ptr(const float* __restrict__ proj,
                                             __half* __restrict__ projT) {
  int e = blockIdx.x * 256 + threadIdx.x;   // 16384
  int n = e >> 6, k = e & 63;
  projT[e] = __float2half_rn(proj[k * 256 + n] * (DN * LOG2E));
}

// ---------------------------------------------------------------------------
// S1 (MFMA) v12: 128x128 tiles, 256 threads, grid (64,12) = 768 blocks ->
// 3 blocks/CU balanced (v9's (32,12) was 1.5/CU lumpy). Register prefetch
// + raw barriers kept.
// ---------------------------------------------------------------------------
__global__ __launch_bounds__(256) void k_qkv(
    const float* __restrict__ A, const float* __restrict__ Wq,
    __half* __restrict__ q, __half* __restrict__ k, __half* __restrict__ v) {
  __shared__ __align__(16) char smem[34816];
  _Float16* Ah = (_Float16*)smem;            // [128][40]
  _Float16* Bh = (_Float16*)(smem + 10240);  // [128][40]
  _Float16* Oh = (_Float16*)smem;            // [128][136] epilogue alias

  const int tid = threadIdx.x;
  const int row0 = blockIdx.x * 128;
  const int col0 = blockIdx.y * 128;
  const int lane = tid & 63, wv = tid >> 6;   // wv 0..3
  const int ln15 = lane & 15, quad = lane >> 4;
  const int m0 = wv * 32;

  f32x4 Cacc[2][8];
  const f32x4 z4 = {0.f, 0.f, 0.f, 0.f};
#pragma unroll
  for (int mi = 0; mi < 2; ++mi)
#pragma unroll
    for (int nt = 0; nt < 8; ++nt) Cacc[mi][nt] = z4;

  const int srow = tid >> 1, sc = (tid & 1) * 16;
  const float* aptr = A + (size_t)(row0 + srow) * DMID + sc;
  const float* bptr = Wq + (size_t)(col0 + srow) * DMID + sc;

  // prologue prefetch (kt = 0)
  float4 ra[4], rb[4];
#pragma unroll
  for (int i = 0; i < 4; ++i) {
    ra[i] = *(const float4*)(aptr + i * 4);
    rb[i] = *(const float4*)(bptr + i * 4);
  }

  for (int kt = 0; kt < DMID; kt += 32) {
    cvt16r(ra, &Ah[srow * 40 + sc]);
    cvt16r(rb, &Bh[srow * 40 + sc]);
    if (kt + 32 < DMID) {
#pragma unroll
      for (int i = 0; i < 4; ++i) {
        ra[i] = *(const float4*)(aptr + kt + 32 + i * 4);
        rb[i] = *(const float4*)(bptr + kt + 32 + i * 4);
      }
    }
    asm volatile("s_waitcnt lgkmcnt(0)" ::: "memory");
    __builtin_amdgcn_s_barrier();
    asm volatile("" ::: "memory");

    f16x8 a0 = *(const f16x8*)&Ah[(m0 + ln15) * 40 + quad * 8];
    f16x8 a1 = *(const f16x8*)&Ah[(m0 + 16 + ln15) * 40 + quad * 8];
#pragma unroll
    for (int nt = 0; nt < 8; ++nt) {
      f16x8 bf = *(const f16x8*)&Bh[(nt * 16 + ln15) * 40 + quad * 8];
      Cacc[0][nt] = __builtin_amdgcn_mfma_f32_16x16x32_f16(a0, bf, Cacc[0][nt], 0, 0, 0);
      Cacc[1][nt] = __builtin_amdgcn_mfma_f32_16x16x32_f16(a1, bf, Cacc[1][nt], 0, 0, 0);
    }
    asm volatile("" ::: "memory");
    __builtin_amdgcn_s_barrier();
    asm volatile("" ::: "memory");
  }
#pragma unroll
  for (int mi = 0; mi < 2; ++mi)
#pragma unroll
    for (int nt = 0; nt < 8; ++nt)
#pragma unroll
      for (int r = 0; r < 4; ++r)
        Oh[(m0 + mi * 16 + quad * 4 + r) * 136 + nt * 16 + ln15] =
            (_Float16)Cacc[mi][nt][r];
  __syncthreads();
  const int tr = tid >> 4, tc = tid & 15;
  const int col = col0 + tc * 8;
  const int hh = col / 192;
  const int rem = col - hh * 192;
  const int t = rem >> 6;
  const int d0 = rem & 63;
  __half* dstb = (t == 0) ? q : ((t == 1) ? k : v);
#pragma unroll
  for (int i = 0; i < 8; ++i) {
    int lrow = tr * 8 + i;
    int grow = row0 + lrow;
    int l = grow >> 2, bb = grow & 3;
    f16x8 val = *(const f16x8*)&Oh[lrow * 136 + tc * 8];
    *(f16x8*)((_Float16*)dstb + (((size_t)(bb * NH + hh) * LSEQ + l) << 6) + d0) = val;
  }
}

// ---------------------------------------------------------------------------
// S2 (MFMA): d' = x @ (DN*LOG2E*proj) (65536x256, K=64) -> fp16 (exp2 domain);
// per-row C = g' + log2(rowsum). 512 threads / 128 rows per block.
// ---------------------------------------------------------------------------
__global__ __launch_bounds__(512) void k_dgemm(
    const __half* __restrict__ qsrc, const __half* __restrict__ ksrc,
    const __half* __restrict__ projT, __half* __restrict__ dqd,
    __half* __restrict__ dkd, float* __restrict__ nq,
    float* __restrict__ nk) {
  __shared__ __align__(16) char smem[37888];
  _Float16* Bt = (_Float16*)smem;             // [256][72]
  float* g_l  = (float*)(smem + 36864);       // [128]
  float* ps_l = (float*)(smem + 37376);       // [128]
  _Float16* Oh = (_Float16*)smem;             // [128][136] epilogue alias

  const int tid = threadIdx.x;
  const __half* src = blockIdx.y ? ksrc : qsrc;
  __half* dst = blockIdx.y ? dkd : dqd;
  float* nrm = blockIdx.y ? nk : nq;
  const size_t r0 = (size_t)blockIdx.x * 128;

  const int lane = tid & 63, wv = tid >> 6;   // wv in 0..7
  const int ln15 = lane & 15, quad = lane >> 4;
  const int m0 = wv * 16;                     // 16 rows per wave, 128 total

#pragma unroll
  for (int it = 0; it < 4; ++it) {
    int e = it * 512 + tid;
    int n = e >> 3, seg = e & 7;
    *(f16x8*)&Bt[n * 72 + seg * 8] =
        *(const f16x8*)((const _Float16*)projT + n * 64 + seg * 8);
  }

  f16x8 afrag[2];
  float ss = 0.f;
  {
    const _Float16* rp = (const _Float16*)src + (r0 + m0 + ln15) * 64;
#pragma unroll
    for (int ks = 0; ks < 2; ++ks) {
      f16x8 x8 = *(const f16x8*)(rp + ks * 32 + quad * 8);
      afrag[ks] = x8;
#pragma unroll
      for (int j = 0; j < 8; ++j) {
        float xv = (float)x8[j];
        ss = fmaf(xv, xv, ss);
      }
    }
    ss += __shfl_xor(ss, 16);
    ss += __shfl_xor(ss, 32);
  }
  if (quad == 0) g_l[m0 + ln15] = 0.5f * DN2 * LOG2E * ss;  // g' (log2 dom)
  __syncthreads();

  f32x4 Cacc[16];
  const f32x4 z4 = {0.f, 0.f, 0.f, 0.f};
#pragma unroll
  for (int nt = 0; nt < 16; ++nt) Cacc[nt] = z4;

#pragma unroll
  for (int ks = 0; ks < 2; ++ks) {
    f16x8 a0 = afrag[ks];
#pragma unroll
    for (int nt = 0; nt < 16; ++nt) {
      f16x8 bf = *(const f16x8*)&Bt[(nt * 16 + ln15) * 72 + ks * 32 + quad * 8];
      Cacc[nt] = __builtin_amdgcn_mfma_f32_16x16x32_f16(a0, bf, Cacc[nt], 0, 0, 0);
    }
  }

  float gv[4], pp[4];
#pragma unroll
  for (int r = 0; r < 4; ++r) {
    gv[r] = g_l[m0 + quad * 4 + r];
    pp[r] = 0.f;
  }
#pragma unroll
  for (int nt = 0; nt < 16; ++nt)
#pragma unroll
    for (int r = 0; r < 4; ++r) {
      float d = Cacc[nt][r];
      pp[r] += exp2a(d - gv[r]) + exp2a(-d - gv[r]);
    }
#pragma unroll
  for (int r = 0; r < 4; ++r) {
    float p = pp[r];
    p += __shfl_xor(p, 1); p += __shfl_xor(p, 2);
    p += __shfl_xor(p, 4); p += __shfl_xor(p, 8);
    if (ln15 == 0) ps_l[m0 + quad * 4 + r] = p;
  }

#pragma unroll
  for (int hf = 0; hf < 2; ++hf) {
    __syncthreads();
#pragma unroll
    for (int nt2 = 0; nt2 < 8; ++nt2) {
      int nt = hf * 8 + nt2;
#pragma unroll
      for (int r = 0; r < 4; ++r)
        Oh[(m0 + quad * 4 + r) * 136 + nt2 * 16 + ln15] =
            (_Float16)Cacc[nt][r];
    }
    __syncthreads();
#pragma unroll
    for (int it = 0; it < 4; ++it) {
      int e = it * 512 + tid;
      int row = e >> 4, seg = e & 15;
      *(f16x8*)((_Float16*)dst + (r0 + row) * 256 + hf * 128 + seg * 8) =
          *(const f16x8*)&Oh[row * 136 + seg * 8];
    }
  }
  if (tid < 128) nrm[r0 + tid] = g_l[tid] + __log2f(ps_l[tid]);
}

// ---------------------------------------------------------------------------
// S3 (MFMA) v8: ONE 512-thread block per chunk; Vt/ck staged once; dk halves
// held in regs across the +/- sign passes. Oh2 aliases kpT with barriers.
// ---------------------------------------------------------------------------
__global__ __launch_bounds__(512) void k_kv(
    const __half* __restrict__ dk, const float* __restrict__ nk,
    const __half* __restrict__ v, __half* __restrict__ KVt,
    float* __restrict__ Ks) {
  __shared__ __align__(16) char smem[52736];
  _Float16* kpT = (_Float16*)smem;            // [128 feat][136 s] = 34816
  _Float16* Vt  = (_Float16*)(smem + 34816);  // [64 d][136 s]   = 17408
  float* ck = (float*)(smem + 52224);         // [128]
  _Float16* Oh2 = (_Float16*)smem;            // [64][136] alias (17408)

  const int tid = threadIdx.x;
  const int cidx = blockIdx.x;
  const size_t rowbase = (size_t)cidx * CHK;
  const int lane = tid & 63, wv = tid >> 6;
  const int ln15 = lane & 15, quad = lane >> 4;

  if (tid < 128) ck[tid] = nk[rowbase + tid];
  {
    int s = tid & 127, dq0 = (tid >> 7) * 16;
    const _Float16* vsrc = (const _Float16*)v + (rowbase + s) * 64 + dq0;
    f16x8 v0 = ((const f16x8*)vsrc)[0];
    f16x8 v1 = ((const f16x8*)vsrc)[1];
#pragma unroll
    for (int j = 0; j < 8; ++j) {
      Vt[(dq0 + j) * 136 + s] = v0[j];
      Vt[(dq0 + 8 + j) * 136 + s] = v1[j];
    }
  }

  const int srow = tid >> 2;
  const int scol = (tid & 3) * 32;

  f16x8 bone;
#pragma unroll
  for (int j = 0; j < 8; ++j)
    bone[j] = (ln15 == 0) ? (_Float16)1.0f : (_Float16)0.0f;

  bool first = true;
#pragma unroll
  for (int cp = 0; cp < 2; ++cp) {
    f16x8 rk[4];
    const _Float16* dsrc =
        (const _Float16*)dk + (rowbase + srow) * 256 + cp * 128 + scol;
#pragma unroll
    for (int it = 0; it < 4; ++it) rk[it] = *(const f16x8*)(dsrc + it * 8);
    float c = ck[srow];
    if (first) { __syncthreads(); c = ck[srow]; }

#pragma unroll
    for (int sg = 0; sg < 2; ++sg) {
      const int i0 = sg * 256 + cp * 128;
      const float fsign = sg ? -1.f : 1.f;
      if (!first) __syncthreads();
      first = false;
#pragma unroll
      for (int it = 0; it < 4; ++it) {
        f16x8 d8 = rk[it];
#pragma unroll
        for (int j = 0; j < 8; ++j)
          kpT[(scol + it * 8 + j) * 136 + srow] =
              (_Float16)exp2a(fmaf((float)d8[j], fsign, -c));
      }
      __syncthreads();

      f32x4 Cacc[4], Kacc;
      const f32x4 z4 = {0.f, 0.f, 0.f, 0.f};
#pragma unroll
      for (int nt = 0; nt < 4; ++nt) Cacc[nt] = z4;
      Kacc = z4;
#pragma unroll
      for (int ks = 0; ks < 4; ++ks) {
        f16x8 a0 = *(const f16x8*)&kpT[(wv * 16 + ln15) * 136 + ks * 32 + quad * 8];
#pragma unroll
        for (int nt = 0; nt < 4; ++nt) {
          f16x8 bV = *(const f16x8*)&Vt[(nt * 16 + ln15) * 136 + ks * 32 + quad * 8];
          Cacc[nt] = __builtin_amdgcn_mfma_f32_16x16x32_f16(a0, bV, Cacc[nt], 0, 0, 0);
        }
        Kacc = __builtin_amdgcn_mfma_f32_16x16x32_f16(a0, bone, Kacc, 0, 0, 0);
      }
      if (ln15 == 0) {
#pragma unroll
        for (int r = 0; r < 4; ++r)
          Ks[(size_t)cidx * 512 + i0 + wv * 16 + quad * 4 + r] = Kacc[r];
      }
      __syncthreads();

#pragma unroll
      for (int nt = 0; nt < 4; ++nt) {
        f16x4 pack = {(_Float16)Cacc[nt][0], (_Float16)Cacc[nt][1],
                      (_Float16)Cacc[nt][2], (_Float16)Cacc[nt][3]};
        *(f16x4*)&Oh2[(nt * 16 + ln15) * 136 + wv * 16 + quad * 4] = pack;
      }
      __syncthreads();
      {
        int d = tid >> 3, part = tid & 7;
        _Float16* dstp =
            (_Float16*)KVt + (size_t)cidx * 32768 + d * 512 + i0 + part * 16;
        const _Float16* srcp = &Oh2[d * 136 + part * 16];
        *(f16x8*)(dstp) = *(const f16x8*)(srcp);
        *(f16x8*)(dstp + 8) = *(const f16x8*)(srcp + 8);
      }
    }
  }
}

// S3c: exclusive prefix over the 16 chunks (per bh) for KVt and Ks.
__global__ __launch_bounds__(256) void k_scan(__half2* __restrict__ KV2,
                                              float* __restrict__ Ks) {
  const int bh = blockIdx.x;
  const int tid = threadIdx.x;
  if (blockIdx.y < 32) {
    uint2* p = (uint2*)(KV2 + (size_t)bh * 262144) + (blockIdx.y * 256 + tid);
    uint2 raw[16];
#pragma unroll
    for (int c = 0; c < 16; ++c) raw[c] = p[c * 8192];
    float ax0 = 0.f, ay0 = 0.f, ax1 = 0.f, ay1 = 0.f;
#pragma unroll
    for (int c = 0; c < 16; ++c) {
      __half2 h0 = *(__half2*)&raw[c].x;
      __half2 h1 = *(__half2*)&raw[c].y;
      float2 f0 = __half22float2(h0), f1 = __half22float2(h1);
      __half2 o0 = __floats2half2_rn(ax0, ay0);
      __half2 o1 = __floats2half2_rn(ax1, ay1);
      uint2 o;
      o.x = *(unsigned*)&o0;
      o.y = *(unsigned*)&o1;
      p[c * 8192] = o;
      ax0 += f0.x; ay0 += f0.y; ax1 += f1.x; ay1 += f1.y;
    }
  } else {
    int i = (blockIdx.y - 32) * 256 + tid;  // 0..511
    float* pk = Ks + (size_t)bh * 8192 + i;
    float vs[16];
#pragma unroll
    for (int c = 0; c < 16; ++c) vs[c] = pk[c * 512];
    float a = 0.f;
#pragma unroll
    for (int c = 0; c < 16; ++c) { pk[c * 512] = a; a += vs[c]; }
  }
}

// ---------------------------------------------------------------------------
// S4 (MFMA) v11 (unchanged, best known): 1-deep q/k + W/Kpre prefetch,
// raw barriers, setprio around MFMA phase.
// ---------------------------------------------------------------------------
__global__ __launch_bounds__(512) void k_attn(
    const __half* __restrict__ dq, const __half* __restrict__ dk,
    const float* __restrict__ nq, const float* __restrict__ nk,
    const __half* __restrict__ v, const __half* __restrict__ KVt,
    const float* __restrict__ Kpre, float* __restrict__ outb) {
  __shared__ __align__(16) char smem[53760];
  _Float16* qpT = (_Float16*)(smem);            // [128][72]
  _Float16* kpT = (_Float16*)(smem + 18432);    // [128][72]
  _Float16* WT  = (_Float16*)(smem + 36864);    // [64][72]
  float*    KpT = (float*)(smem + 46080);       // [64]
  float* cq_l   = (float*)(smem + 46336);       // [128]
  float* ck_l   = (float*)(smem + 46848);       // [128]
  // Epilogue aliases (K-loop tiles dead by then):
  _Float16* S_h = (_Float16*)(smem);            // [2][64][136] = 34816
  _Float16* Vt  = (_Float16*)(smem + 34816);    // [64][136] -> ends 52224
  float* den1_l = (float*)(smem + 52224);       // [128]
  float* den2_l = (float*)(smem + 52736);       // [128]
  float* invd_l = (float*)(smem + 53248);       // [128] -> ends 53760

  const int tid = threadIdx.x;
  const int cidx = blockIdx.x;
  const int cc = cidx & 15, bh = cidx >> 4;
  const size_t rowb = (size_t)cidx * 128;
  const int lane = tid & 63;
  const int wv = tid >> 6;        // 0..7
  const int H = wv >> 2;          // q-half this wave owns
  const int m0 = (wv & 3) * 16;   // 16-row tile within the half
  const int ln15 = lane & 15, quad = lane >> 4;

  if (tid < 128) cq_l[tid] = nq[rowb + tid];
  else if (tid < 256) ck_l[tid - 128] = nk[rowb + tid - 128];
  __syncthreads();

  const int c8 = tid & 7;
  const int r9 = tid >> 3;        // 0..63; rows r9 and r9+64 per pass
  const int csrc = (c8 & 3) * 8;
  const float sgnf = (c8 < 4) ? 1.f : -1.f;

  const _Float16* qsrc = (const _Float16*)dq + (rowb + r9) * 256 + csrc;
  const _Float16* ksrc = (const _Float16*)dk + (rowb + r9) * 256 + csrc;
  const _Float16* wsrc = (const _Float16*)KVt + (size_t)cidx * 32768 +
                         r9 * 512 + ((c8 < 4) ? 0 : 256) + csrc;
  const float* kpsrc = Kpre + (size_t)cidx * 512 +
                       ((tid < 32) ? tid : (tid < 64 ? 224 + tid : 0));

  float cq[2], ck2[2];
#pragma unroll
  for (int p = 0; p < 2; ++p) {
    cq[p] = cq_l[r9 + p * 64];
    ck2[p] = ck_l[r9 + p * 64];
  }

  // prologue prefetch (it = 0): q/k + W/Kpre
  f16x8 rq[2], rk[2];
#pragma unroll
  for (int p = 0; p < 2; ++p) {
    rq[p] = *(const f16x8*)(qsrc + p * 16384);
    rk[p] = *(const f16x8*)(ksrc + p * 16384);
  }
  f16x8 wcur = *(const f16x8*)(wsrc);
  float kpcur = kpsrc[0];

  f32x4 Sacc[8], Oacc[4], Dacc;
  const f32x4 z4 = {0.f, 0.f, 0.f, 0.f};
#pragma unroll
  for (int nt = 0; nt < 8; ++nt) Sacc[nt] = z4;
#pragma unroll
  for (int nt = 0; nt < 4; ++nt) Oacc[nt] = z4;
  Dacc = z4;

  const int NSw = H ? 8 : 4;

  for (int it = 0; it < 8; ++it) {
    const int kb = it * 32;
    // next iter's W/Kpre: issued first (oldest), consumed next iteration
    f16x8 wnxt;
    float kpnxt = 0.f;
    if (it < 7) {
      wnxt = *(const f16x8*)(wsrc + kb + 32);
      kpnxt = kpsrc[kb + 32];
    }

    // exp2 staging from prefetched regs
#pragma unroll
    for (int p = 0; p < 2; ++p) {
      f16x8 d = rq[p], t;
#pragma unroll
      for (int j = 0; j < 8; ++j)
        t[j] = (_Float16)exp2a(fmaf((float)d[j], sgnf, -cq[p]));
      *(f16x8*)&qpT[(r9 + p * 64) * 72 + c8 * 8] = t;
    }
#pragma unroll
    for (int p = 0; p < 2; ++p) {
      f16x8 d = rk[p], t;
#pragma unroll
      for (int j = 0; j < 8; ++j)
        t[j] = (_Float16)exp2a(fmaf((float)d[j], sgnf, -ck2[p]));
      *(f16x8*)&kpT[(r9 + p * 64) * 72 + c8 * 8] = t;
    }

    // issue next tile's q/k loads (stay in flight across raw barriers)
    if (it < 7) {
#pragma unroll
      for (int p = 0; p < 2; ++p) {
        rq[p] = *(const f16x8*)(qsrc + p * 16384 + kb + 32);
        rk[p] = *(const f16x8*)(ksrc + p * 16384 + kb + 32);
      }
    }
    // W/Kpre staged from regs loaded LAST iteration (full-iter coverage)
    *(f16x8*)&WT[r9 * 72 + c8 * 8] = wcur;
    if (tid < 64) KpT[tid] = kpcur;

    asm volatile("s_waitcnt lgkmcnt(0)" ::: "memory");
    __builtin_amdgcn_s_barrier();
    asm volatile("" ::: "memory");

    __builtin_amdgcn_s_setprio(1);
#pragma unroll
    for (int ks = 0; ks < 2; ++ks) {
      f16x8 a0 = *(const f16x8*)&qpT[(H * 64 + m0 + ln15) * 72 + ks * 32 + quad * 8];
#pragma unroll
      for (int nt = 0; nt < 4; ++nt) {
        f16x8 bf = *(const f16x8*)&kpT[(nt * 16 + ln15) * 72 + ks * 32 + quad * 8];
        Sacc[nt] = __builtin_amdgcn_mfma_f32_16x16x32_f16(a0, bf, Sacc[nt], 0, 0, 0);
      }
      if (H) {
#pragma unroll
        for (int nt = 4; nt < 8; ++nt) {
          f16x8 bf = *(const f16x8*)&kpT[(nt * 16 + ln15) * 72 + ks * 32 + quad * 8];
          Sacc[nt] = __builtin_amdgcn_mfma_f32_16x16x32_f16(a0, bf, Sacc[nt], 0, 0, 0);
        }
      }
#pragma unroll
      for (int nt = 0; nt < 4; ++nt) {
        f16x8 bw = *(const f16x8*)&WT[(nt * 16 + ln15) * 72 + ks * 32 + quad * 8];
        Oacc[nt] = __builtin_amdgcn_mfma_f32_16x16x32_f16(a0, bw, Oacc[nt], 0, 0, 0);
      }
      f16x8 bk;
#pragma unroll
      for (int j = 0; j < 8; ++j)
        bk[j] = (ln15 == 0) ? (_Float16)KpT[ks * 32 + quad * 8 + j]
                            : (_Float16)0.f;
      Dacc = __builtin_amdgcn_mfma_f32_16x16x32_f16(a0, bk, Dacc, 0, 0, 0);
    }
    __builtin_amdgcn_s_setprio(0);

    asm volatile("" ::: "memory");
    __builtin_amdgcn_s_barrier();
    asm volatile("" ::: "memory");

    if (it < 7) { wcur = wnxt; kpcur = kpnxt; }
  }

  // ---- epilogue ----
  if (ln15 == 0) {
#pragma unroll
    for (int r = 0; r < 4; ++r)
      den2_l[H * 64 + m0 + quad * 4 + r] = Dacc[r];
  }
  {
    _Float16* S_me = S_h + H * 8704;
    float dp[4] = {0.f, 0.f, 0.f, 0.f};
#pragma unroll
    for (int nt = 0; nt < 8; ++nt) {
      if (nt < NSw) {
        int s = nt * 16 + ln15;
#pragma unroll
        for (int r = 0; r < 4; ++r) {
          int tl = m0 + quad * 4 + r;
          float vsv = (s <= H * 64 + tl) ? Sacc[nt][r] : 0.f;
          dp[r] += vsv;
          S_me[tl * 136 + s] = (_Float16)vsv;
        }
      }
    }
#pragma unroll
    for (int r = 0; r < 4; ++r) {
      float p = dp[r];
      p += __shfl_xor(p, 1); p += __shfl_xor(p, 2);
      p += __shfl_xor(p, 4); p += __shfl_xor(p, 8);
      if (ln15 == 0) den1_l[H * 64 + m0 + quad * 4 + r] = p;
    }
  }
  {
    int s = tid & 127, d0v = (tid >> 7) * 16;
    const _Float16* vsrc = (const _Float16*)v + (rowb + s) * 64 + d0v;
    f16x8 v0 = ((const f16x8*)vsrc)[0];
    f16x8 v1 = ((const f16x8*)vsrc)[1];
#pragma unroll
    for (int j = 0; j < 8; ++j) {
      Vt[(d0v + j) * 136 + s] = v0[j];
      Vt[(d0v + 8 + j) * 136 + s] = v1[j];
    }
  }
  __syncthreads();
  if (tid < 128)
    invd_l[tid] = SCALE / (den1_l[tid] + den2_l[tid] + EPS_ATTN);
  __syncthreads();
  {
    _Float16* S_me = S_h + H * 8704;
#pragma unroll
    for (int ks = 0; ks < 4; ++ks) {
      if (ks < (H ? 4 : 2)) {
        f16x8 aS0 = *(const f16x8*)&S_me[(m0 + ln15) * 136 + ks * 32 + quad * 8];
#pragma unroll
        for (int nt = 0; nt < 4; ++nt) {
          f16x8 bV = *(const f16x8*)&Vt[(nt * 16 + ln15) * 136 + ks * 32 + quad * 8];
          Oacc[nt] = __builtin_amdgcn_mfma_f32_16x16x32_f16(aS0, bV, Oacc[nt], 0, 0, 0);
        }
      }
    }
  }
  const int b = bh >> 3, hh = bh & 7;
  float ivv[4];
#pragma unroll
  for (int r = 0; r < 4; ++r)
    ivv[r] = invd_l[H * 64 + m0 + quad * 4 + r];
#pragma unroll
  for (int nt = 0; nt < 4; ++nt) {
    int dcol = nt * 16 + ln15;
#pragma unroll
    for (int r = 0; r < 4; ++r) {
      int l = cc * 128 + H * 64 + m0 + quad * 4 + r;
      outb[((size_t)l * 4 + b) * 512 + hh * 64 + dcol] = Oacc[nt][r] * ivv[r];
    }
  }
}

// ---------------------------------------------------------------------------
// S5a (MFMA) v12: 64x128 tiles, 256 threads, grid (128,4) = 512 blocks ->
// 2 blocks/CU (was 256 blocks = 1/CU = 1 wave/SIMD, zero latency hiding).
// Register prefetch + raw barriers kept.
// ---------------------------------------------------------------------------
__global__ __launch_bounds__(256) void k_oproj(
    const float* __restrict__ A, const float* __restrict__ Wo,
    const float* __restrict__ hres, float* __restrict__ xout) {
  __shared__ __align__(16) char smem[17408];
  _Float16* Ah = (_Float16*)smem;            // [64][40]  = 5120
  _Float16* Bh = (_Float16*)(smem + 5120);   // [128][40] = 10240 -> 15360
  _Float16* Oh = (_Float16*)smem;            // [64][136] = 17408 (alias)

  const int tid = threadIdx.x;
  const int row0 = blockIdx.x * 64;
  const int col0 = blockIdx.y * 128;
  const int lane = tid & 63, wv = tid >> 6;   // wv 0..3
  const int ln15 = lane & 15, quad = lane >> 4;
  const int m0 = wv * 16;                     // 16 rows per wave

  f32x4 Cacc[8];
  const f32x4 z4 = {0.f, 0.f, 0.f, 0.f};
#pragma unroll
  for (int nt = 0; nt < 8; ++nt) Cacc[nt] = z4;

  const int arow = tid >> 2, asc = (tid & 3) * 8;   // A: 64 rows x 32 cols
  const int brow = tid >> 1, bsc = (tid & 1) * 16;  // B: 128 rows x 32 cols
  const float* aptr = A + (size_t)(row0 + arow) * DMID + asc;
  const float* bptr = Wo + (size_t)(col0 + brow) * DMID + bsc;

  float4 ra[2], rb[4];
#pragma unroll
  for (int i = 0; i < 2; ++i) ra[i] = *(const float4*)(aptr + i * 4);
#pragma unroll
  for (int i = 0; i < 4; ++i) rb[i] = *(const float4*)(bptr + i * 4);

  for (int kt = 0; kt < DMID; kt += 32) {
    cvt8r(ra, &Ah[arow * 40 + asc]);
    cvt16r(rb, &Bh[brow * 40 + bsc]);
    if (kt + 32 < DMID) {
#pragma unroll
      for (int i = 0; i < 2; ++i)
        ra[i] = *(const float4*)(aptr + kt + 32 + i * 4);
#pragma unroll
      for (int i = 0; i < 4; ++i)
        rb[i] = *(const float4*)(bptr + kt + 32 + i * 4);
    }
    asm volatile("s_waitcnt lgkmcnt(0)" ::: "memory");
    __builtin_amdgcn_s_barrier();
    asm volatile("" ::: "memory");

    f16x8 a0 = *(const f16x8*)&Ah[(m0 + ln15) * 40 + quad * 8];
#pragma unroll
    for (int nt = 0; nt < 8; ++nt) {
      f16x8 bf = *(const f16x8*)&Bh[(nt * 16 + ln15) * 40 + quad * 8];
      Cacc[nt] = __builtin_amdgcn_mfma_f32_16x16x32_f16(a0, bf, Cacc[nt], 0, 0, 0);
    }
    asm volatile("" ::: "memory");
    __builtin_amdgcn_s_barrier();
    asm volatile("" ::: "memory");
  }
#pragma unroll
  for (int nt = 0; nt < 8; ++nt)
#pragma unroll
    for (int r = 0; r < 4; ++r)
      Oh[(m0 + quad * 4 + r) * 136 + nt * 16 + ln15] = (_Float16)Cacc[nt][r];
  __syncthreads();
  const int tr = tid >> 4, tc = tid & 15;   // 16 row-groups x 4 rows
#pragma unroll
  for (int i = 0; i < 4; ++i) {
    int lrow = tr * 4 + i;
    int grow = row0 + lrow;
    size_t base = (size_t)grow * 512 + col0 + tc * 8;
    f16x8 o = *(const f16x8*)&Oh[lrow * 136 + tc * 8];
    float4 h0 = *(const float4*)(hres + base);
    float4 h1 = *(const float4*)(hres + base + 4);
    *(float4*)(xout + base) =
        make_float4((float)o[0] + h0.x, (float)o[1] + h0.y,
                    (float)o[2] + h0.z, (float)o[3] + h0.w);
    *(float4*)(xout + base + 4) =
        make_float4((float)o[4] + h1.x, (float)o[5] + h1.y,
                    (float)o[6] + h1.z, (float)o[7] + h1.w);
  }
}

// S5b: in-place LayerNorm over last dim (512).
__global__ __launch_bounds__(256) void k_ln(float* __restrict__ x,
                                            const float* __restrict__ g,
                                            const float* __restrict__ bta) {
  __shared__ float ws_[4], wq_[4];
  const int row = blockIdx.x;
  const int tid = threadIdx.x;
  float2 vv = *(const float2*)(x + (size_t)row * 512 + tid * 2);
  float s = vv.x + vv.y;
  float sq = vv.x * vv.x + vv.y * vv.y;
#pragma unroll
  for (int off = 1; off < 64; off <<= 1) {
    s += __shfl_xor(s, off, 64);
    sq += __shfl_xor(sq, off, 64);
  }
  if ((tid & 63) == 0) { ws_[tid >> 6] = s; wq_[tid >> 6] = sq; }
  __syncthreads();
  s = ws_[0] + ws_[1] + ws_[2] + ws_[3];
  sq = wq_[0] + wq_[1] + wq_[2] + wq_[3];
  float mu = s * (1.f / 512.f);
  float var = sq * (1.f / 512.f) - mu * mu;
  float rstd = rsqrtf(var + EPS_LN);
  int c = tid * 2;
  float2 o;
  o.x = (vv.x - mu) * rstd * g[c] + bta[c];
  o.y = (vv.y - mu) * rstd * g[c + 1] + bta[c + 1];
  *(float2*)(x + (size_t)row * 512 + c) = o;
}

// ---------------------------------------------------------------------------
extern "C" void kernel_launch(void* const* d_in, const int* in_sizes, int n_in,
                              void* d_out, int out_size, void* d_ws,
                              size_t ws_size, hipStream_t stream) {
  const float* h    = (const float*)d_in[0];
  const float* wqkv = (const float*)d_in[1];
  const float* wo   = (const float*)d_in[2];
  const float* g    = (const float*)d_in[3];
  const float* bta  = (const float*)d_in[4];
  const float* proj = (const float*)d_in[5];
  float* out = (float*)d_out;
  char* wsb = (char*)d_ws;

  __half* q   = (__half*)(wsb + 0);           //  8,388,608 B
  __half* kb  = (__half*)(wsb + 8388608);     //  8,388,608 B
  __half* vb  = (__half*)(wsb + 16777216);    //  8,388,608 B
  __half* dq  = (__half*)(wsb + 25165824);    // 33,554,432 B
  __half* dk  = (__half*)(wsb + 58720256);    // 33,554,432 B
  float*  nq  = (float*)(wsb + 92274688);     //    262,144 B (C per q-row)
  float*  nk  = (float*)(wsb + 92798976);     //    262,144 B (C per k-row)
  __half* KVt = (__half*)(wsb + 93323264);    // 33,554,432 B  (cidx,d,feat)
  float*  Ks  = (float*)(wsb + 126877696);    //  1,048,576 B
  __half* pT  = (__half*)(wsb + 127926272);   //     32,768 B
  float* outb = (float*)(wsb + 0);            // aliases q+kb (dead by then)

  if (ws_size < 127959040ull) {
    float val = 1000.0f + (float)(ws_size >> 20);
    k_diag<<<(out_size + 255) / 256, 256, 0, stream>>>(out, out_size, val);
    return;
  }

  k_ptr  <<<dim3(64), 256, 0, stream>>>(proj, pT);
  k_qkv  <<<dim3(64, 12), 256, 0, stream>>>(h, wqkv, q, kb, vb);
  k_dgemm<<<dim3(512, 2), 512, 0, stream>>>(q, kb, pT, dq, dk, nq, nk);
  k_kv   <<<dim3(512), 512, 0, stream>>>(dk, nk, vb, KVt, Ks);
  k_scan <<<dim3(32, 34), 256, 0, stream>>>((__half2*)KVt, Ks);
  k_attn <<<dim3(512), 512, 0, stream>>>(dq, dk, nq, nk, vb, KVt, Ks, outb);
  k_oproj<<<dim3(128, 4), 256, 0, stream>>>(outb, wo, h, out);
  k_ln   <<<dim3(8192), 256, 0, stream>>>(out, g, bta);
}

// Round 13
// 223.167 us; speedup vs baseline: 1.0150x; 1.0150x over previous
//
#include <hip/hip_runtime.h>
#include <hip/hip_fp16.h>
#include <math.h>

#define LSEQ 2048
#define NB 4
#define NH 8
#define DMID 512
#define CHK 128
#define SCALE 0.125f
#define DN 0.35355339059327373f   // 64^{-0.25}
#define DN2 0.125f                // DN*DN
#define LOG2E 1.4426950408889634f
#define EPS_ATTN 1e-5f
#define EPS_LN 1e-5f

typedef _Float16 f16x8 __attribute__((ext_vector_type(8)));
typedef _Float16 f16x4 __attribute__((ext_vector_type(4)));
typedef float f32x4 __attribute__((ext_vector_type(4)));

// Raw v_exp_f32 (2^x). Non-volatile: pure, freely schedulable.
__device__ __forceinline__ float exp2a(float x) {
  float r;
  asm("v_exp_f32 %0, %1" : "=v"(r) : "v"(x));
  return r;
}

__device__ __forceinline__ void cvt16(const float* __restrict__ p,
                                      _Float16* __restrict__ dst) {
  float4 a = *(const float4*)p, b = *(const float4*)(p + 4);
  float4 c = *(const float4*)(p + 8), d = *(const float4*)(p + 12);
  f16x8 t0 = {(_Float16)a.x, (_Float16)a.y, (_Float16)a.z, (_Float16)a.w,
              (_Float16)b.x, (_Float16)b.y, (_Float16)b.z, (_Float16)b.w};
  f16x8 t1 = {(_Float16)c.x, (_Float16)c.y, (_Float16)c.z, (_Float16)c.w,
              (_Float16)d.x, (_Float16)d.y, (_Float16)d.z, (_Float16)d.w};
  *(f16x8*)dst = t0;
  *(f16x8*)(dst + 8) = t1;
}

// Convert 4 prefetched float4 regs -> 16 fp16 in LDS.
__device__ __forceinline__ void cvt16r(const float4* __restrict__ r,
                                       _Float16* __restrict__ dst) {
  f16x8 t0 = {(_Float16)r[0].x, (_Float16)r[0].y, (_Float16)r[0].z,
              (_Float16)r[0].w, (_Float16)r[1].x, (_Float16)r[1].y,
              (_Float16)r[1].z, (_Float16)r[1].w};
  f16x8 t1 = {(_Float16)r[2].x, (_Float16)r[2].y, (_Float16)r[2].z,
              (_Float16)r[2].w, (_Float16)r[3].x, (_Float16)r[3].y,
              (_Float16)r[3].z, (_Float16)r[3].w};
  *(f16x8*)dst = t0;
  *(f16x8*)(dst + 8) = t1;
}

// Convert 2 prefetched float4 regs -> 8 fp16 in LDS.
__device__ __forceinline__ void cvt8r(const float4* __restrict__ r,
                                      _Float16* __restrict__ dst) {
  f16x8 t0 = {(_Float16)r[0].x, (_Float16)r[0].y, (_Float16)r[0].z,
              (_Float16)r[0].w, (_Float16)r[1].x, (_Float16)r[1].y,
              (_Float16)r[1].z, (_Float16)r[1].w};
  *(f16x8*)dst = t0;
}

// Diagnostic: encode ws_size (MiB) into the output if workspace too small.
__global__ void k_diag(float* out, int n, float val) {
  int i = blockIdx.x * 256 + threadIdx.x;
  if (i < n) out[i] = val;
}

// Once-per-launch: projT[n][k] = DN*LOG2E * proj[k][n], fp16.
__global__ __launch_bounds__(256) void k_ptr(const float* __restrict__ proj,
                                             __half* __restrict__ projT) {
  int e = blockIdx.x * 256 + threadIdx.x;   // 16384
  int n = e >> 6, k = e & 63;
  projT[e] = __float2half_rn(proj[k * 256 + n] * (DN * LOG2E));
}

// ---------------------------------------------------------------------------
// S1 (MFMA) v9 (v11 best): 256x128 tiles, 512 threads, grid (32,12).
// Register prefetch of next K-tile + raw barriers.
// ---------------------------------------------------------------------------
__global__ __launch_bounds__(512) void k_qkv(
    const float* __restrict__ A, const float* __restrict__ Wq,
    __half* __restrict__ q, __half* __restrict__ k, __half* __restrict__ v) {
  __shared__ __align__(16) char smem[34816];
  _Float16* Ah = (_Float16*)smem;            // [256][40] = 20480
  _Float16* Bh = (_Float16*)(smem + 20480);  // [128][40] = 10240
  _Float16* Oh = (_Float16*)smem;            // [128][136] epilogue alias

  const int tid = threadIdx.x;
  const int row0 = blockIdx.x * 256;
  const int col0 = blockIdx.y * 128;
  const int lane = tid & 63, wv = tid >> 6;   // wv 0..7
  const int ln15 = lane & 15, quad = lane >> 4;
  const int m0 = wv * 32;                     // 32 rows per wave

  f32x4 Cacc[2][8];
  const f32x4 z4 = {0.f, 0.f, 0.f, 0.f};
#pragma unroll
  for (int mi = 0; mi < 2; ++mi)
#pragma unroll
    for (int nt = 0; nt < 8; ++nt) Cacc[mi][nt] = z4;

  const int sarow = tid >> 1, sac = (tid & 1) * 16;
  const float* aptr = A + (size_t)(row0 + sarow) * DMID + sac;
  const float* bptr = Wq + (size_t)(col0 + sarow) * DMID + sac;

  // prologue prefetch (kt = 0)
  float4 ra[4], rb[4];
#pragma unroll
  for (int i = 0; i < 4; ++i) ra[i] = *(const float4*)(aptr + i * 4);
  if (tid < 256) {
#pragma unroll
    for (int i = 0; i < 4; ++i) rb[i] = *(const float4*)(bptr + i * 4);
  }

  for (int kt = 0; kt < DMID; kt += 32) {
    cvt16r(ra, &Ah[sarow * 40 + sac]);
    if (tid < 256) cvt16r(rb, &Bh[sarow * 40 + sac]);
    if (kt + 32 < DMID) {
#pragma unroll
      for (int i = 0; i < 4; ++i)
        ra[i] = *(const float4*)(aptr + kt + 32 + i * 4);
      if (tid < 256) {
#pragma unroll
        for (int i = 0; i < 4; ++i)
          rb[i] = *(const float4*)(bptr + kt + 32 + i * 4);
      }
    }
    asm volatile("s_waitcnt lgkmcnt(0)" ::: "memory");
    __builtin_amdgcn_s_barrier();
    asm volatile("" ::: "memory");

    f16x8 a0 = *(const f16x8*)&Ah[(m0 + ln15) * 40 + quad * 8];
    f16x8 a1 = *(const f16x8*)&Ah[(m0 + 16 + ln15) * 40 + quad * 8];
#pragma unroll
    for (int nt = 0; nt < 8; ++nt) {
      f16x8 bf = *(const f16x8*)&Bh[(nt * 16 + ln15) * 40 + quad * 8];
      Cacc[0][nt] = __builtin_amdgcn_mfma_f32_16x16x32_f16(a0, bf, Cacc[0][nt], 0, 0, 0);
      Cacc[1][nt] = __builtin_amdgcn_mfma_f32_16x16x32_f16(a1, bf, Cacc[1][nt], 0, 0, 0);
    }
    asm volatile("" ::: "memory");
    __builtin_amdgcn_s_barrier();
    asm volatile("" ::: "memory");
  }

  const int tr = tid >> 4, tc = tid & 15;     // tr 0..31: 4 rows each
  const int col = col0 + tc * 8;
  const int hh = col / 192;
  const int rem = col - hh * 192;
  const int t = rem >> 6;
  const int d0 = rem & 63;
  __half* dstb = (t == 0) ? q : ((t == 1) ? k : v);

#pragma unroll
  for (int hf = 0; hf < 2; ++hf) {
    if ((wv >> 2) == hf) {
      int lm = (wv & 3) * 32;
#pragma unroll
      for (int mi = 0; mi < 2; ++mi)
#pragma unroll
        for (int nt = 0; nt < 8; ++nt)
#pragma unroll
          for (int r = 0; r < 4; ++r)
            Oh[(lm + mi * 16 + quad * 4 + r) * 136 + nt * 16 + ln15] =
                (_Float16)Cacc[mi][nt][r];
    }
    __syncthreads();
#pragma unroll
    for (int i = 0; i < 4; ++i) {
      int lrow = tr * 4 + i;
      int grow = row0 + hf * 128 + lrow;
      int l = grow >> 2, bb = grow & 3;
      f16x8 val = *(const f16x8*)&Oh[lrow * 136 + tc * 8];
      *(f16x8*)((_Float16*)dstb + (((size_t)(bb * NH + hh) * LSEQ + l) << 6) + d0) = val;
    }
    __syncthreads();
  }
}

// ---------------------------------------------------------------------------
// S2 (MFMA): d' = x @ (DN*LOG2E*proj) (65536x256, K=64) -> fp16 (exp2 domain);
// per-row C = g' + log2(rowsum). 512 threads / 128 rows per block.
// ---------------------------------------------------------------------------
__global__ __launch_bounds__(512) void k_dgemm(
    const __half* __restrict__ qsrc, const __half* __restrict__ ksrc,
    const __half* __restrict__ projT, __half* __restrict__ dqd,
    __half* __restrict__ dkd, float* __restrict__ nq,
    float* __restrict__ nk) {
  __shared__ __align__(16) char smem[37888];
  _Float16* Bt = (_Float16*)smem;             // [256][72]
  float* g_l  = (float*)(smem + 36864);       // [128]
  float* ps_l = (float*)(smem + 37376);       // [128]
  _Float16* Oh = (_Float16*)smem;             // [128][136] epilogue alias

  const int tid = threadIdx.x;
  const __half* src = blockIdx.y ? ksrc : qsrc;
  __half* dst = blockIdx.y ? dkd : dqd;
  float* nrm = blockIdx.y ? nk : nq;
  const size_t r0 = (size_t)blockIdx.x * 128;

  const int lane = tid & 63, wv = tid >> 6;   // wv in 0..7
  const int ln15 = lane & 15, quad = lane >> 4;
  const int m0 = wv * 16;                     // 16 rows per wave, 128 total

#pragma unroll
  for (int it = 0; it < 4; ++it) {
    int e = it * 512 + tid;
    int n = e >> 3, seg = e & 7;
    *(f16x8*)&Bt[n * 72 + seg * 8] =
        *(const f16x8*)((const _Float16*)projT + n * 64 + seg * 8);
  }

  f16x8 afrag[2];
  float ss = 0.f;
  {
    const _Float16* rp = (const _Float16*)src + (r0 + m0 + ln15) * 64;
#pragma unroll
    for (int ks = 0; ks < 2; ++ks) {
      f16x8 x8 = *(const f16x8*)(rp + ks * 32 + quad * 8);
      afrag[ks] = x8;
#pragma unroll
      for (int j = 0; j < 8; ++j) {
        float xv = (float)x8[j];
        ss = fmaf(xv, xv, ss);
      }
    }
    ss += __shfl_xor(ss, 16);
    ss += __shfl_xor(ss, 32);
  }
  if (quad == 0) g_l[m0 + ln15] = 0.5f * DN2 * LOG2E * ss;  // g' (log2 dom)
  __syncthreads();

  f32x4 Cacc[16];
  const f32x4 z4 = {0.f, 0.f, 0.f, 0.f};
#pragma unroll
  for (int nt = 0; nt < 16; ++nt) Cacc[nt] = z4;

#pragma unroll
  for (int ks = 0; ks < 2; ++ks) {
    f16x8 a0 = afrag[ks];
#pragma unroll
    for (int nt = 0; nt < 16; ++nt) {
      f16x8 bf = *(const f16x8*)&Bt[(nt * 16 + ln15) * 72 + ks * 32 + quad * 8];
      Cacc[nt] = __builtin_amdgcn_mfma_f32_16x16x32_f16(a0, bf, Cacc[nt], 0, 0, 0);
    }
  }

  float gv[4], pp[4];
#pragma unroll
  for (int r = 0; r < 4; ++r) {
    gv[r] = g_l[m0 + quad * 4 + r];
    pp[r] = 0.f;
  }
#pragma unroll
  for (int nt = 0; nt < 16; ++nt)
#pragma unroll
    for (int r = 0; r < 4; ++r) {
      float d = Cacc[nt][r];
      pp[r] += exp2a(d - gv[r]) + exp2a(-d - gv[r]);
    }
#pragma unroll
  for (int r = 0; r < 4; ++r) {
    float p = pp[r];
    p += __shfl_xor(p, 1); p += __shfl_xor(p, 2);
    p += __shfl_xor(p, 4); p += __shfl_xor(p, 8);
    if (ln15 == 0) ps_l[m0 + quad * 4 + r] = p;
  }

#pragma unroll
  for (int hf = 0; hf < 2; ++hf) {
    __syncthreads();
#pragma unroll
    for (int nt2 = 0; nt2 < 8; ++nt2) {
      int nt = hf * 8 + nt2;
#pragma unroll
      for (int r = 0; r < 4; ++r)
        Oh[(m0 + quad * 4 + r) * 136 + nt2 * 16 + ln15] =
            (_Float16)Cacc[nt][r];
    }
    __syncthreads();
#pragma unroll
    for (int it = 0; it < 4; ++it) {
      int e = it * 512 + tid;
      int row = e >> 4, seg = e & 15;
      *(f16x8*)((_Float16*)dst + (r0 + row) * 256 + hf * 128 + seg * 8) =
          *(const f16x8*)&Oh[row * 136 + seg * 8];
    }
  }
  if (tid < 128) nrm[r0 + tid] = g_l[tid] + __log2f(ps_l[tid]);
}

// ---------------------------------------------------------------------------
// S3 (MFMA) v8: ONE 512-thread block per chunk; Vt/ck staged once; dk halves
// held in regs across the +/- sign passes. Oh2 aliases kpT with barriers.
// ---------------------------------------------------------------------------
__global__ __launch_bounds__(512) void k_kv(
    const __half* __restrict__ dk, const float* __restrict__ nk,
    const __half* __restrict__ v, __half* __restrict__ KVt,
    float* __restrict__ Ks) {
  __shared__ __align__(16) char smem[52736];
  _Float16* kpT = (_Float16*)smem;            // [128 feat][136 s] = 34816
  _Float16* Vt  = (_Float16*)(smem + 34816);  // [64 d][136 s]   = 17408
  float* ck = (float*)(smem + 52224);         // [128]
  _Float16* Oh2 = (_Float16*)smem;            // [64][136] alias (17408)

  const int tid = threadIdx.x;
  const int cidx = blockIdx.x;
  const size_t rowbase = (size_t)cidx * CHK;
  const int lane = tid & 63, wv = tid >> 6;
  const int ln15 = lane & 15, quad = lane >> 4;

  if (tid < 128) ck[tid] = nk[rowbase + tid];
  {
    int s = tid & 127, dq0 = (tid >> 7) * 16;
    const _Float16* vsrc = (const _Float16*)v + (rowbase + s) * 64 + dq0;
    f16x8 v0 = ((const f16x8*)vsrc)[0];
    f16x8 v1 = ((const f16x8*)vsrc)[1];
#pragma unroll
    for (int j = 0; j < 8; ++j) {
      Vt[(dq0 + j) * 136 + s] = v0[j];
      Vt[(dq0 + 8 + j) * 136 + s] = v1[j];
    }
  }

  const int srow = tid >> 2;
  const int scol = (tid & 3) * 32;

  f16x8 bone;
#pragma unroll
  for (int j = 0; j < 8; ++j)
    bone[j] = (ln15 == 0) ? (_Float16)1.0f : (_Float16)0.0f;

  bool first = true;
#pragma unroll
  for (int cp = 0; cp < 2; ++cp) {
    f16x8 rk[4];
    const _Float16* dsrc =
        (const _Float16*)dk + (rowbase + srow) * 256 + cp * 128 + scol;
#pragma unroll
    for (int it = 0; it < 4; ++it) rk[it] = *(const f16x8*)(dsrc + it * 8);
    float c = ck[srow];
    if (first) { __syncthreads(); c = ck[srow]; }

#pragma unroll
    for (int sg = 0; sg < 2; ++sg) {
      const int i0 = sg * 256 + cp * 128;
      const float fsign = sg ? -1.f : 1.f;
      if (!first) __syncthreads();
      first = false;
#pragma unroll
      for (int it = 0; it < 4; ++it) {
        f16x8 d8 = rk[it];
#pragma unroll
        for (int j = 0; j < 8; ++j)
          kpT[(scol + it * 8 + j) * 136 + srow] =
              (_Float16)exp2a(fmaf((float)d8[j], fsign, -c));
      }
      __syncthreads();

      f32x4 Cacc[4], Kacc;
      const f32x4 z4 = {0.f, 0.f, 0.f, 0.f};
#pragma unroll
      for (int nt = 0; nt < 4; ++nt) Cacc[nt] = z4;
      Kacc = z4;
#pragma unroll
      for (int ks = 0; ks < 4; ++ks) {
        f16x8 a0 = *(const f16x8*)&kpT[(wv * 16 + ln15) * 136 + ks * 32 + quad * 8];
#pragma unroll
        for (int nt = 0; nt < 4; ++nt) {
          f16x8 bV = *(const f16x8*)&Vt[(nt * 16 + ln15) * 136 + ks * 32 + quad * 8];
          Cacc[nt] = __builtin_amdgcn_mfma_f32_16x16x32_f16(a0, bV, Cacc[nt], 0, 0, 0);
        }
        Kacc = __builtin_amdgcn_mfma_f32_16x16x32_f16(a0, bone, Kacc, 0, 0, 0);
      }
      if (ln15 == 0) {
#pragma unroll
        for (int r = 0; r < 4; ++r)
          Ks[(size_t)cidx * 512 + i0 + wv * 16 + quad * 4 + r] = Kacc[r];
      }
      __syncthreads();

#pragma unroll
      for (int nt = 0; nt < 4; ++nt) {
        f16x4 pack = {(_Float16)Cacc[nt][0], (_Float16)Cacc[nt][1],
                      (_Float16)Cacc[nt][2], (_Float16)Cacc[nt][3]};
        *(f16x4*)&Oh2[(nt * 16 + ln15) * 136 + wv * 16 + quad * 4] = pack;
      }
      __syncthreads();
      {
        int d = tid >> 3, part = tid & 7;
        _Float16* dstp =
            (_Float16*)KVt + (size_t)cidx * 32768 + d * 512 + i0 + part * 16;
        const _Float16* srcp = &Oh2[d * 136 + part * 16];
        *(f16x8*)(dstp) = *(const f16x8*)(srcp);
        *(f16x8*)(dstp + 8) = *(const f16x8*)(srcp + 8);
      }
    }
  }
}

// S3c: exclusive prefix over the 16 chunks (per bh) for KVt and Ks.
__global__ __launch_bounds__(256) void k_scan(__half2* __restrict__ KV2,
                                              float* __restrict__ Ks) {
  const int bh = blockIdx.x;
  const int tid = threadIdx.x;
  if (blockIdx.y < 32) {
    uint2* p = (uint2*)(KV2 + (size_t)bh * 262144) + (blockIdx.y * 256 + tid);
    uint2 raw[16];
#pragma unroll
    for (int c = 0; c < 16; ++c) raw[c] = p[c * 8192];
    float ax0 = 0.f, ay0 = 0.f, ax1 = 0.f, ay1 = 0.f;
#pragma unroll
    for (int c = 0; c < 16; ++c) {
      __half2 h0 = *(__half2*)&raw[c].x;
      __half2 h1 = *(__half2*)&raw[c].y;
      float2 f0 = __half22float2(h0), f1 = __half22float2(h1);
      __half2 o0 = __floats2half2_rn(ax0, ay0);
      __half2 o1 = __floats2half2_rn(ax1, ay1);
      uint2 o;
      o.x = *(unsigned*)&o0;
      o.y = *(unsigned*)&o1;
      p[c * 8192] = o;
      ax0 += f0.x; ay0 += f0.y; ax1 += f1.x; ay1 += f1.y;
    }
  } else {
    int i = (blockIdx.y - 32) * 256 + tid;  // 0..511
    float* pk = Ks + (size_t)bh * 8192 + i;
    float vs[16];
#pragma unroll
    for (int c = 0; c < 16; ++c) vs[c] = pk[c * 512];
    float a = 0.f;
#pragma unroll
    for (int c = 0; c < 16; ++c) { pk[c * 512] = a; a += vs[c]; }
  }
}

// ---------------------------------------------------------------------------
// S4 (MFMA) v11 (unchanged, best known): 1-deep q/k + W/Kpre prefetch,
// raw barriers, setprio around MFMA phase.
// ---------------------------------------------------------------------------
__global__ __launch_bounds__(512) void k_attn(
    const __half* __restrict__ dq, const __half* __restrict__ dk,
    const float* __restrict__ nq, const float* __restrict__ nk,
    const __half* __restrict__ v, const __half* __restrict__ KVt,
    const float* __restrict__ Kpre, float* __restrict__ outb) {
  __shared__ __align__(16) char smem[53760];
  _Float16* qpT = (_Float16*)(smem);            // [128][72]
  _Float16* kpT = (_Float16*)(smem + 18432);    // [128][72]
  _Float16* WT  = (_Float16*)(smem + 36864);    // [64][72]
  float*    KpT = (float*)(smem + 46080);       // [64]
  float* cq_l   = (float*)(smem + 46336);       // [128]
  float* ck_l   = (float*)(smem + 46848);       // [128]
  // Epilogue aliases (K-loop tiles dead by then):
  _Float16* S_h = (_Float16*)(smem);            // [2][64][136] = 34816
  _Float16* Vt  = (_Float16*)(smem + 34816);    // [64][136] -> ends 52224
  float* den1_l = (float*)(smem + 52224);       // [128]
  float* den2_l = (float*)(smem + 52736);       // [128]
  float* invd_l = (float*)(smem + 53248);       // [128] -> ends 53760

  const int tid = threadIdx.x;
  const int cidx = blockIdx.x;
  const int cc = cidx & 15, bh = cidx >> 4;
  const size_t rowb = (size_t)cidx * 128;
  const int lane = tid & 63;
  const int wv = tid >> 6;        // 0..7
  const int H = wv >> 2;          // q-half this wave owns
  const int m0 = (wv & 3) * 16;   // 16-row tile within the half
  const int ln15 = lane & 15, quad = lane >> 4;

  if (tid < 128) cq_l[tid] = nq[rowb + tid];
  else if (tid < 256) ck_l[tid - 128] = nk[rowb + tid - 128];
  __syncthreads();

  const int c8 = tid & 7;
  const int r9 = tid >> 3;        // 0..63; rows r9 and r9+64 per pass
  const int csrc = (c8 & 3) * 8;
  const float sgnf = (c8 < 4) ? 1.f : -1.f;

  const _Float16* qsrc = (const _Float16*)dq + (rowb + r9) * 256 + csrc;
  const _Float16* ksrc = (const _Float16*)dk + (rowb + r9) * 256 + csrc;
  const _Float16* wsrc = (const _Float16*)KVt + (size_t)cidx * 32768 +
                         r9 * 512 + ((c8 < 4) ? 0 : 256) + csrc;
  const float* kpsrc = Kpre + (size_t)cidx * 512 +
                       ((tid < 32) ? tid : (tid < 64 ? 224 + tid : 0));

  float cq[2], ck2[2];
#pragma unroll
  for (int p = 0; p < 2; ++p) {
    cq[p] = cq_l[r9 + p * 64];
    ck2[p] = ck_l[r9 + p * 64];
  }

  // prologue prefetch (it = 0): q/k + W/Kpre
  f16x8 rq[2], rk[2];
#pragma unroll
  for (int p = 0; p < 2; ++p) {
    rq[p] = *(const f16x8*)(qsrc + p * 16384);
    rk[p] = *(const f16x8*)(ksrc + p * 16384);
  }
  f16x8 wcur = *(const f16x8*)(wsrc);
  float kpcur = kpsrc[0];

  f32x4 Sacc[8], Oacc[4], Dacc;
  const f32x4 z4 = {0.f, 0.f, 0.f, 0.f};
#pragma unroll
  for (int nt = 0; nt < 8; ++nt) Sacc[nt] = z4;
#pragma unroll
  for (int nt = 0; nt < 4; ++nt) Oacc[nt] = z4;
  Dacc = z4;

  const int NSw = H ? 8 : 4;

  for (int it = 0; it < 8; ++it) {
    const int kb = it * 32;
    // next iter's W/Kpre: issued first (oldest), consumed next iteration
    f16x8 wnxt;
    float kpnxt = 0.f;
    if (it < 7) {
      wnxt = *(const f16x8*)(wsrc + kb + 32);
      kpnxt = kpsrc[kb + 32];
    }

    // exp2 staging from prefetched regs
#pragma unroll
    for (int p = 0; p < 2; ++p) {
      f16x8 d = rq[p], t;
#pragma unroll
      for (int j = 0; j < 8; ++j)
        t[j] = (_Float16)exp2a(fmaf((float)d[j], sgnf, -cq[p]));
      *(f16x8*)&qpT[(r9 + p * 64) * 72 + c8 * 8] = t;
    }
#pragma unroll
    for (int p = 0; p < 2; ++p) {
      f16x8 d = rk[p], t;
#pragma unroll
      for (int j = 0; j < 8; ++j)
        t[j] = (_Float16)exp2a(fmaf((float)d[j], sgnf, -ck2[p]));
      *(f16x8*)&kpT[(r9 + p * 64) * 72 + c8 * 8] = t;
    }

    // issue next tile's q/k loads (stay in flight across raw barriers)
    if (it < 7) {
#pragma unroll
      for (int p = 0; p < 2; ++p) {
        rq[p] = *(const f16x8*)(qsrc + p * 16384 + kb + 32);
        rk[p] = *(const f16x8*)(ksrc + p * 16384 + kb + 32);
      }
    }
    // W/Kpre staged from regs loaded LAST iteration (full-iter coverage)
    *(f16x8*)&WT[r9 * 72 + c8 * 8] = wcur;
    if (tid < 64) KpT[tid] = kpcur;

    asm volatile("s_waitcnt lgkmcnt(0)" ::: "memory");
    __builtin_amdgcn_s_barrier();
    asm volatile("" ::: "memory");

    __builtin_amdgcn_s_setprio(1);
#pragma unroll
    for (int ks = 0; ks < 2; ++ks) {
      f16x8 a0 = *(const f16x8*)&qpT[(H * 64 + m0 + ln15) * 72 + ks * 32 + quad * 8];
#pragma unroll
      for (int nt = 0; nt < 4; ++nt) {
        f16x8 bf = *(const f16x8*)&kpT[(nt * 16 + ln15) * 72 + ks * 32 + quad * 8];
        Sacc[nt] = __builtin_amdgcn_mfma_f32_16x16x32_f16(a0, bf, Sacc[nt], 0, 0, 0);
      }
      if (H) {
#pragma unroll
        for (int nt = 4; nt < 8; ++nt) {
          f16x8 bf = *(const f16x8*)&kpT[(nt * 16 + ln15) * 72 + ks * 32 + quad * 8];
          Sacc[nt] = __builtin_amdgcn_mfma_f32_16x16x32_f16(a0, bf, Sacc[nt], 0, 0, 0);
        }
      }
#pragma unroll
      for (int nt = 0; nt < 4; ++nt) {
        f16x8 bw = *(const f16x8*)&WT[(nt * 16 + ln15) * 72 + ks * 32 + quad * 8];
        Oacc[nt] = __builtin_amdgcn_mfma_f32_16x16x32_f16(a0, bw, Oacc[nt], 0, 0, 0);
      }
      f16x8 bk;
#pragma unroll
      for (int j = 0; j < 8; ++j)
        bk[j] = (ln15 == 0) ? (_Float16)KpT[ks * 32 + quad * 8 + j]
                            : (_Float16)0.f;
      Dacc = __builtin_amdgcn_mfma_f32_16x16x32_f16(a0, bk, Dacc, 0, 0, 0);
    }
    __builtin_amdgcn_s_setprio(0);

    asm volatile("" ::: "memory");
    __builtin_amdgcn_s_barrier();
    asm volatile("" ::: "memory");

    if (it < 7) { wcur = wnxt; kpcur = kpnxt; }
  }

  // ---- epilogue ----
  if (ln15 == 0) {
#pragma unroll
    for (int r = 0; r < 4; ++r)
      den2_l[H * 64 + m0 + quad * 4 + r] = Dacc[r];
  }
  {
    _Float16* S_me = S_h + H * 8704;
    float dp[4] = {0.f, 0.f, 0.f, 0.f};
#pragma unroll
    for (int nt = 0; nt < 8; ++nt) {
      if (nt < NSw) {
        int s = nt * 16 + ln15;
#pragma unroll
        for (int r = 0; r < 4; ++r) {
          int tl = m0 + quad * 4 + r;
          float vsv = (s <= H * 64 + tl) ? Sacc[nt][r] : 0.f;
          dp[r] += vsv;
          S_me[tl * 136 + s] = (_Float16)vsv;
        }
      }
    }
#pragma unroll
    for (int r = 0; r < 4; ++r) {
      float p = dp[r];
      p += __shfl_xor(p, 1); p += __shfl_xor(p, 2);
      p += __shfl_xor(p, 4); p += __shfl_xor(p, 8);
      if (ln15 == 0) den1_l[H * 64 + m0 + quad * 4 + r] = p;
    }
  }
  {
    int s = tid & 127, d0v = (tid >> 7) * 16;
    const _Float16* vsrc = (const _Float16*)v + (rowb + s) * 64 + d0v;
    f16x8 v0 = ((const f16x8*)vsrc)[0];
    f16x8 v1 = ((const f16x8*)vsrc)[1];
#pragma unroll
    for (int j = 0; j < 8; ++j) {
      Vt[(d0v + j) * 136 + s] = v0[j];
      Vt[(d0v + 8 + j) * 136 + s] = v1[j];
    }
  }
  __syncthreads();
  if (tid < 128)
    invd_l[tid] = SCALE / (den1_l[tid] + den2_l[tid] + EPS_ATTN);
  __syncthreads();
  {
    _Float16* S_me = S_h + H * 8704;
#pragma unroll
    for (int ks = 0; ks < 4; ++ks) {
      if (ks < (H ? 4 : 2)) {
        f16x8 aS0 = *(const f16x8*)&S_me[(m0 + ln15) * 136 + ks * 32 + quad * 8];
#pragma unroll
        for (int nt = 0; nt < 4; ++nt) {
          f16x8 bV = *(const f16x8*)&Vt[(nt * 16 + ln15) * 136 + ks * 32 + quad * 8];
          Oacc[nt] = __builtin_amdgcn_mfma_f32_16x16x32_f16(aS0, bV, Oacc[nt], 0, 0, 0);
        }
      }
    }
  }
  const int b = bh >> 3, hh = bh & 7;
  float ivv[4];
#pragma unroll
  for (int r = 0; r < 4; ++r)
    ivv[r] = invd_l[H * 64 + m0 + quad * 4 + r];
#pragma unroll
  for (int nt = 0; nt < 4; ++nt) {
    int dcol = nt * 16 + ln15;
#pragma unroll
    for (int r = 0; r < 4; ++r) {
      int l = cc * 128 + H * 64 + m0 + quad * 4 + r;
      outb[((size_t)l * 4 + b) * 512 + hh * 64 + dcol] = Oacc[nt][r] * ivv[r];
    }
  }
}

// ---------------------------------------------------------------------------
// S5a (MFMA) v12 (kept): 64x128 tiles, 256 threads, grid (128,4) = 512
// blocks -> 2 blocks/CU. Register prefetch + raw barriers.
// ---------------------------------------------------------------------------
__global__ __launch_bounds__(256) void k_oproj(
    const float* __restrict__ A, const float* __restrict__ Wo,
    const float* __restrict__ hres, float* __restrict__ xout) {
  __shared__ __align__(16) char smem[17408];
  _Float16* Ah = (_Float16*)smem;            // [64][40]  = 5120
  _Float16* Bh = (_Float16*)(smem + 5120);   // [128][40] = 10240 -> 15360
  _Float16* Oh = (_Float16*)smem;            // [64][136] = 17408 (alias)

  const int tid = threadIdx.x;
  const int row0 = blockIdx.x * 64;
  const int col0 = blockIdx.y * 128;
  const int lane = tid & 63, wv = tid >> 6;   // wv 0..3
  const int ln15 = lane & 15, quad = lane >> 4;
  const int m0 = wv * 16;                     // 16 rows per wave

  f32x4 Cacc[8];
  const f32x4 z4 = {0.f, 0.f, 0.f, 0.f};
#pragma unroll
  for (int nt = 0; nt < 8; ++nt) Cacc[nt] = z4;

  const int arow = tid >> 2, asc = (tid & 3) * 8;   // A: 64 rows x 32 cols
  const int brow = tid >> 1, bsc = (tid & 1) * 16;  // B: 128 rows x 32 cols
  const float* aptr = A + (size_t)(row0 + arow) * DMID + asc;
  const float* bptr = Wo + (size_t)(col0 + brow) * DMID + bsc;

  float4 ra[2], rb[4];
#pragma unroll
  for (int i = 0; i < 2; ++i) ra[i] = *(const float4*)(aptr + i * 4);
#pragma unroll
  for (int i = 0; i < 4; ++i) rb[i] = *(const float4*)(bptr + i * 4);

  for (int kt = 0; kt < DMID; kt += 32) {
    cvt8r(ra, &Ah[arow * 40 + asc]);
    cvt16r(rb, &Bh[brow * 40 + bsc]);
    if (kt + 32 < DMID) {
#pragma unroll
      for (int i = 0; i < 2; ++i)
        ra[i] = *(const float4*)(aptr + kt + 32 + i * 4);
#pragma unroll
      for (int i = 0; i < 4; ++i)
        rb[i] = *(const float4*)(bptr + kt + 32 + i * 4);
    }
    asm volatile("s_waitcnt lgkmcnt(0)" ::: "memory");
    __builtin_amdgcn_s_barrier();
    asm volatile("" ::: "memory");

    f16x8 a0 = *(const f16x8*)&Ah[(m0 + ln15) * 40 + quad * 8];
#pragma unroll
    for (int nt = 0; nt < 8; ++nt) {
      f16x8 bf = *(const f16x8*)&Bh[(nt * 16 + ln15) * 40 + quad * 8];
      Cacc[nt] = __builtin_amdgcn_mfma_f32_16x16x32_f16(a0, bf, Cacc[nt], 0, 0, 0);
    }
    asm volatile("" ::: "memory");
    __builtin_amdgcn_s_barrier();
    asm volatile("" ::: "memory");
  }
#pragma unroll
  for (int nt = 0; nt < 8; ++nt)
#pragma unroll
    for (int r = 0; r < 4; ++r)
      Oh[(m0 + quad * 4 + r) * 136 + nt * 16 + ln15] = (_Float16)Cacc[nt][r];
  __syncthreads();
  const int tr = tid >> 4, tc = tid & 15;   // 16 row-groups x 4 rows
#pragma unroll
  for (int i = 0; i < 4; ++i) {
    int lrow = tr * 4 + i;
    int grow = row0 + lrow;
    size_t base = (size_t)grow * 512 + col0 + tc * 8;
    f16x8 o = *(const f16x8*)&Oh[lrow * 136 + tc * 8];
    float4 h0 = *(const float4*)(hres + base);
    float4 h1 = *(const float4*)(hres + base + 4);
    *(float4*)(xout + base) =
        make_float4((float)o[0] + h0.x, (float)o[1] + h0.y,
                    (float)o[2] + h0.z, (float)o[3] + h0.w);
    *(float4*)(xout + base + 4) =
        make_float4((float)o[4] + h1.x, (float)o[5] + h1.y,
                    (float)o[6] + h1.z, (float)o[7] + h1.w);
  }
}

// S5b: in-place LayerNorm over last dim (512).
__global__ __launch_bounds__(256) void k_ln(float* __restrict__ x,
                                            const float* __restrict__ g,
                                            const float* __restrict__ bta) {
  __shared__ float ws_[4], wq_[4];
  const int row = blockIdx.x;
  const int tid = threadIdx.x;
  float2 vv = *(const float2*)(x + (size_t)row * 512 + tid * 2);
  float s = vv.x + vv.y;
  float sq = vv.x * vv.x + vv.y * vv.y;
#pragma unroll
  for (int off = 1; off < 64; off <<= 1) {
    s += __shfl_xor(s, off, 64);
    sq += __shfl_xor(sq, off, 64);
  }
  if ((tid & 63) == 0) { ws_[tid >> 6] = s; wq_[tid >> 6] = sq; }
  __syncthreads();
  s = ws_[0] + ws_[1] + ws_[2] + ws_[3];
  sq = wq_[0] + wq_[1] + wq_[2] + wq_[3];
  float mu = s * (1.f / 512.f);
  float var = sq * (1.f / 512.f) - mu * mu;
  float rstd = rsqrtf(var + EPS_LN);
  int c = tid * 2;
  float2 o;
  o.x = (vv.x - mu) * rstd * g[c] + bta[c];
  o.y = (vv.y - mu) * rstd * g[c + 1] + bta[c + 1];
  *(float2*)(x + (size_t)row * 512 + c) = o;
}

// ---------------------------------------------------------------------------
extern "C" void kernel_launch(void* const* d_in, const int* in_sizes, int n_in,
                              void* d_out, int out_size, void* d_ws,
                              size_t ws_size, hipStream_t stream) {
  const float* h    = (const float*)d_in[0];
  const float* wqkv = (const float*)d_in[1];
  const float* wo   = (const float*)d_in[2];
  const float* g    = (const float*)d_in[3];
  const float* bta  = (const float*)d_in[4];
  const float* proj = (const float*)d_in[5];
  float* out = (float*)d_out;
  char* wsb = (char*)d_ws;

  __half* q   = (__half*)(wsb + 0);           //  8,388,608 B
  __half* kb  = (__half*)(wsb + 8388608);     //  8,388,608 B
  __half* vb  = (__half*)(wsb + 16777216);    //  8,388,608 B
  __half* dq  = (__half*)(wsb + 25165824);    // 33,554,432 B
  __half* dk  = (__half*)(wsb + 58720256);    // 33,554,432 B
  float*  nq  = (float*)(wsb + 92274688);     //    262,144 B (C per q-row)
  float*  nk  = (float*)(wsb + 92798976);     //    262,144 B (C per k-row)
  __half* KVt = (__half*)(wsb + 93323264);    // 33,554,432 B  (cidx,d,feat)
  float*  Ks  = (float*)(wsb + 126877696);    //  1,048,576 B
  __half* pT  = (__half*)(wsb + 127926272);   //     32,768 B
  float* outb = (float*)(wsb + 0);            // aliases q+kb (dead by then)

  if (ws_size < 127959040ull) {
    float val = 1000.0f + (float)(ws_size >> 20);
    k_diag<<<(out_size + 255) / 256, 256, 0, stream>>>(out, out_size, val);
    return;
  }

  k_ptr  <<<dim3(64), 256, 0, stream>>>(proj, pT);
  k_qkv  <<<dim3(32, 12), 512, 0, stream>>>(h, wqkv, q, kb, vb);
  k_dgemm<<<dim3(512, 2), 512, 0, stream>>>(q, kb, pT, dq, dk, nq, nk);
  k_kv   <<<dim3(512), 512, 0, stream>>>(dk, nk, vb, KVt, Ks);
  k_scan <<<dim3(32, 34), 256, 0, stream>>>((__half2*)KVt, Ks);
  k_attn <<<dim3(512), 512, 0, stream>>>(dq, dk, nq, nk, vb, KVt, Ks, outb);
  k_oproj<<<dim3(128, 4), 256, 0, stream>>>(outb, wo, h, out);
  k_ln   <<<dim3(8192), 256, 0, stream>>>(out, g, bta);
}